// Round 5
// baseline (169.116 us; speedup 1.0000x reference)
//
#include <hip/hip_runtime.h>

// Depthwise 4x4 FIR blur, pad (2,2)/(2,2), NCHW fp32.
// x: [16,256,128,128] -> out: [16,256,129,129]
//
// blur_main: block = 1 image, 8 waves, NO barriers. Wave = autonomous
// pipeline over a 16-out-row strip (wave 7: +row 128): private 6-slot LDS
// ring of input row-PAIRS (slot = 2 rows = 1 KB, one global_load_lds each),
// tail-counted vmcnt (never 0 mid-loop), ds_read_b128 window reads, lane
// owns 2 output rows x 4 cols. Covers out cols 0..125.
// blur_edge: out cols 126..128 for all rows (window = aligned float4 at
// input col 124; cols 128,129 are zero pad).

#define WAITV(NSTR) do {                                                     \
        asm volatile("s_waitcnt vmcnt(" NSTR ")" ::: "memory");              \
        __builtin_amdgcn_sched_barrier(0);                                   \
    } while (0)
#define WAITL() do {                                                         \
        asm volatile("s_waitcnt lgkmcnt(0)" ::: "memory");                   \
        __builtin_amdgcn_sched_barrier(0);                                   \
    } while (0)

__global__ __launch_bounds__(512, 6) void blur_main(
    const float* __restrict__ x,
    const float* __restrict__ kern,
    float* __restrict__ out)
{
    // 8 waves x 6 pair-slots x 256 floats = 48 KB
    __shared__ __align__(16) float lds[8 * 6 * 256];

    const int tid  = threadIdx.x;
    const int wv   = tid >> 6;        // strip id 0..7
    const int lane = tid & 63;
    const int h    = lane >> 5;       // row-half within iteration
    const int g    = lane & 31;       // col group: out cols 4g-2..4g+1
    const int r0   = wv << 4;         // strip base output row

    const float* __restrict__ xi = x + (size_t)blockIdx.x * (128 * 128);
    float* __restrict__ oi = out + (size_t)blockIdx.x * (129 * 129);

    float w[4][4];
#pragma unroll
    for (int p = 0; p < 4; ++p)
#pragma unroll
        for (int q = 0; q < 4; ++q)
            w[p][q] = kern[4 * p + q];

    float* const wbase = &lds[wv * 1536];

    // pair q holds input rows (r0-2+2q, r0-2+2q+1), q = 0..9, slot q%6.
    // OOB rows are clamp-loaded dummies, zero-substituted at compute.
#define STAGEPAIR(Q) do {                                                    \
        int p0_ = r0 - 2 + 2 * (Q);                                          \
        p0_ = p0_ < 0 ? 0 : (p0_ > 126 ? 126 : p0_);                         \
        const float* src_ = xi + (size_t)p0_ * 128 + (lane << 2);            \
        const float* dst_ = wbase + ((Q) % 6) * 256;                         \
        __builtin_amdgcn_global_load_lds(                                    \
            (const __attribute__((address_space(1))) unsigned int*)src_,     \
            (__attribute__((address_space(3))) unsigned int*)dst_,           \
            16, 0, 0);                                                       \
    } while (0)

    // out col j = 4g-2+k uses input cols j-2..j+1; av = cols 4g-4..4g-1,
    // bv = cols 4g..4g+3.
#define FMA4(O0, O1, O2, O3, AV, BV, P) do {                                 \
        O0 = fmaf(AV.x, w[P][0], O0);                                        \
        O0 = fmaf(AV.y, w[P][1], O0);                                        \
        O0 = fmaf(AV.z, w[P][2], O0);                                        \
        O0 = fmaf(AV.w, w[P][3], O0);                                        \
        O1 = fmaf(AV.y, w[P][0], O1);                                        \
        O1 = fmaf(AV.z, w[P][1], O1);                                        \
        O1 = fmaf(AV.w, w[P][2], O1);                                        \
        O1 = fmaf(BV.x, w[P][3], O1);                                        \
        O2 = fmaf(AV.z, w[P][0], O2);                                        \
        O2 = fmaf(AV.w, w[P][1], O2);                                        \
        O2 = fmaf(BV.x, w[P][2], O2);                                        \
        O2 = fmaf(BV.y, w[P][3], O2);                                        \
        O3 = fmaf(AV.w, w[P][0], O3);                                        \
        O3 = fmaf(BV.x, w[P][1], O3);                                        \
        O3 = fmaf(BV.y, w[P][2], O3);                                        \
        O3 = fmaf(BV.z, w[P][3], O3);                                        \
    } while (0)

    // Iteration I: lane computes out rows rA = r0+4I+2h and rA+1.
    // Window input rows r0-2+4I+2h+m, m=0..4 -> pair q = 2I+h+(m>>1),
    // row-in-pair = m&1. Row rA gets weight row p=m (m<4); rA+1 gets p=m-1.
#define CITER(I) do {                                                        \
        float oA0=0.f, oA1=0.f, oA2=0.f, oA3=0.f;                            \
        float oB0=0.f, oB1=0.f, oB2=0.f, oB3=0.f;                            \
        _Pragma("unroll")                                                    \
        for (int m = 0; m < 5; ++m) {                                        \
            const int K = (2 * (I) + (m >> 1)) % 6;                          \
            int sl = K + h; sl = (sl >= 6) ? (sl - 6) : sl;                  \
            const int rowv = r0 - 2 + 4 * (I) + 2 * h + m;                   \
            const bool okr = (unsigned)rowv < 128u;                          \
            const float* pa = wbase + sl * 256 + (m & 1) * 128 + 4 * g;      \
            float4 av = make_float4(0.f, 0.f, 0.f, 0.f);                     \
            float4 bv = make_float4(0.f, 0.f, 0.f, 0.f);                     \
            if (okr && g) av = *(const float4*)(pa - 4);                     \
            if (okr)      bv = *(const float4*)pa;                           \
            if (m < 4) FMA4(oA0, oA1, oA2, oA3, av, bv, m);                  \
            if (m > 0) FMA4(oB0, oB1, oB2, oB3, av, bv, (m - 1));            \
        }                                                                    \
        float* po = oi + (size_t)(r0 + 4 * (I) + 2 * h) * 129 + 4 * g - 2;   \
        if (g) { po[0] = oA0; po[1] = oA1; }                                 \
        po[2] = oA2; po[3] = oA3;                                            \
        po += 129;                                                           \
        if (g) { po[0] = oB0; po[1] = oB1; }                                 \
        po[2] = oB2; po[3] = oB3;                                            \
    } while (0)
    // per-wave VMEM per CITER: 8 stores (exec-masked stores still issue).

    // ---- per-wave pipeline (loads L0..L9 = STAGEPAIR(0..9)) ----
    STAGEPAIR(0); STAGEPAIR(1); STAGEPAIR(2);
    STAGEPAIR(3); STAGEPAIR(4); STAGEPAIR(5);

    WAITV("2");                  // L0..L3 retired (C0 needs q0..q3)
    CITER(0);
    WAITL(); STAGEPAIR(6); STAGEPAIR(7);     // slots 0,1 (reads drained)
    WAITV("10");                 // younger than L5: 8 st + L6,L7 -> L5 retired
    CITER(1);
    WAITL(); STAGEPAIR(8); STAGEPAIR(9);     // slots 2,3
    WAITV("10");                 // younger than L7: 8 st + L8,L9 -> L7 retired
    CITER(2);
    WAITV("8");                  // younger than L9: 8 st -> L9 retired
    CITER(3);

    if (wv == 7) {
        // out row 128: window rows 126..129 (128,129 zero); pair q=8, slot 2.
        float oT0=0.f, oT1=0.f, oT2=0.f, oT3=0.f;
        const float* pa = wbase + 2 * 256 + 4 * g;
        float4 av = make_float4(0.f, 0.f, 0.f, 0.f);
        float4 bv;
        if (g) av = *(const float4*)(pa - 4);
        bv = *(const float4*)pa;
        FMA4(oT0, oT1, oT2, oT3, av, bv, 0);           // row 126, p=0
        av = make_float4(0.f, 0.f, 0.f, 0.f);
        if (g) av = *(const float4*)(pa + 128 - 4);
        bv = *(const float4*)(pa + 128);
        FMA4(oT0, oT1, oT2, oT3, av, bv, 1);           // row 127, p=1
        if (!h) {
            float* po = oi + (size_t)128 * 129 + 4 * g - 2;
            if (g) { po[0] = oT0; po[1] = oT1; }
            po[2] = oT2; po[3] = oT3;
        }
    }

#undef STAGEPAIR
#undef FMA4
#undef CITER
}

// out cols 126..128, all 129 rows, all 4096 images. Window = input cols
// 124..127 (one aligned float4); cols 128,129 are zero pad.
__global__ __launch_bounds__(256) void blur_edge(
    const float* __restrict__ x,
    const float* __restrict__ kern,
    float* __restrict__ out)
{
    const int id  = blockIdx.x * 256 + threadIdx.x;   // 2064*256 = 528384 exact
    const int img = id / 129;
    const int r   = id - img * 129;

    float w[4][4];
#pragma unroll
    for (int p = 0; p < 4; ++p)
#pragma unroll
        for (int q = 0; q < 4; ++q)
            w[p][q] = kern[4 * p + q];

    const float* xi = x + (size_t)img * (128 * 128) + 124;
    float e0 = 0.f, e1 = 0.f, e2 = 0.f;
#pragma unroll
    for (int p = 0; p < 4; ++p) {
        const int rr = r - 2 + p;
        float4 v = make_float4(0.f, 0.f, 0.f, 0.f);
        if ((unsigned)rr < 128u) v = *(const float4*)(xi + (size_t)rr * 128);
        e0 = fmaf(v.x, w[p][0], e0);
        e0 = fmaf(v.y, w[p][1], e0);
        e0 = fmaf(v.z, w[p][2], e0);
        e0 = fmaf(v.w, w[p][3], e0);
        e1 = fmaf(v.y, w[p][0], e1);
        e1 = fmaf(v.z, w[p][1], e1);
        e1 = fmaf(v.w, w[p][2], e1);
        e2 = fmaf(v.z, w[p][0], e2);
        e2 = fmaf(v.w, w[p][1], e2);
    }
    float* po = out + (size_t)img * (129 * 129) + (size_t)r * 129 + 126;
    po[0] = e0; po[1] = e1; po[2] = e2;
}

extern "C" void kernel_launch(void* const* d_in, const int* in_sizes, int n_in,
                              void* d_out, int out_size, void* d_ws, size_t ws_size,
                              hipStream_t stream) {
    const float* x    = (const float*)d_in[0];
    const float* kern = (const float*)d_in[1];
    float* out        = (float*)d_out;

    hipLaunchKernelGGL(blur_main, dim3(4096), dim3(512), 0, stream, x, kern, out);
    hipLaunchKernelGGL(blur_edge, dim3(2064), dim3(256), 0, stream, x, kern, out);
}

// Round 6
// 112.188 us; speedup vs baseline: 1.5074x; 1.5074x over previous
//
#include <hip/hip_runtime.h>

// Depthwise 4x4 FIR blur, pad (2,2)/(2,2), NCHW fp32.
// x: [16,256,128,128] -> out: [16,256,129,129]
//
// Block = half image (64 output rows; s==1 also row 128), 512 threads.
// Stage all 66 valid input rows (33 x 1KB global_load_lds) + zero the 2 pad
// rows in LDS, ONE __syncthreads, then compute. LDS slot k = input row
// 64s-2+k (k=0..67, 34 KB -> 4 blocks/CU = 32 waves/CU). Thread = 4 output
// cols (g=tid&31) x 4 rows (c=tid>>5), register ring of 4 LDS rows via
// ds_read_b128. Cols 126..128 folded into g==31 lanes (guarded).

__global__ __launch_bounds__(512) void blur_half(
    const float* __restrict__ x,
    const float* __restrict__ kern,
    float* __restrict__ out)
{
    __shared__ __align__(16) float lds[68 * 128];   // 34 KB

    const int tid  = threadIdx.x;
    const int bid  = blockIdx.x;
    const int img  = bid >> 1;
    const int s    = bid & 1;        // half: out rows [64s, 64s+64)
    const int wv   = tid >> 6;
    const int lane = tid & 63;

    const float* __restrict__ xi = x + (size_t)img * (128 * 128);
    float* __restrict__ oi = out + (size_t)img * (129 * 129);

    // ---- stage: pair p = LDS slots (2p, 2p+1) = input rows 64s-2+2p, +1.
    // Valid pairs: s==0 -> p=1..33 (rows 0..65); s==1 -> p=0..32 (rows 62..127).
    const int P0 = s ? 0 : 1;
    const int P1 = s ? 32 : 33;
    for (int p = P0 + wv; p <= P1; p += 8) {
        const int row = 64 * s - 2 + 2 * p;
        const float* src = xi + (size_t)row * 128 + (lane << 2);
        const float* dst = &lds[p * 256];
        __builtin_amdgcn_global_load_lds(
            (const __attribute__((address_space(1))) unsigned int*)src,
            (__attribute__((address_space(3))) unsigned int*)dst, 16, 0, 0);
    }
    // zero pad rows (disjoint from staged slots)
    if (tid < 256) {
        if (s == 0) lds[tid] = 0.0f;              // slots 0,1  (rows -2,-1)
        else        lds[66 * 128 + tid] = 0.0f;   // slots 66,67 (rows 128,129)
    }

    // 4x4 weights; uniform -> SGPRs
    float w[4][4];
#pragma unroll
    for (int p = 0; p < 4; ++p)
#pragma unroll
        for (int q = 0; q < 4; ++q)
            w[p][q] = kern[4 * p + q];

    __syncthreads();

    // ---- compute ----
    const int c  = tid >> 5;         // row subchunk 0..15 (4 rows each)
    const int g  = tid & 31;         // col group: out cols 4g-2 .. 4g+1
    const bool lv = (g >= 1);

    float xv[4][8];

    // out row i = 64s+4c+j has window input rows i-2..i+1 = slots 4c+j..4c+j+3
#define LLOAD(S, KK) do {                                                    \
        const float* pb_ = &lds[(4 * c + (KK)) * 128 + 4 * g - 4];           \
        float4 a_ = make_float4(0.f, 0.f, 0.f, 0.f);                         \
        if (lv) a_ = *(const float4*)pb_;                                    \
        float4 b_ = *(const float4*)(pb_ + 4);                               \
        xv[S][0] = a_.x; xv[S][1] = a_.y; xv[S][2] = a_.z; xv[S][3] = a_.w;  \
        xv[S][4] = b_.x; xv[S][5] = b_.y; xv[S][6] = b_.z; xv[S][7] = b_.w;  \
    } while (0)

#define ACCP(S, P) do {                                                      \
        o0 = fmaf(xv[S][0], w[P][0], o0);                                    \
        o1 = fmaf(xv[S][1], w[P][0], o1);                                    \
        o2 = fmaf(xv[S][2], w[P][0], o2);                                    \
        o3 = fmaf(xv[S][3], w[P][0], o3);                                    \
        o0 = fmaf(xv[S][1], w[P][1], o0);                                    \
        o1 = fmaf(xv[S][2], w[P][1], o1);                                    \
        o2 = fmaf(xv[S][3], w[P][1], o2);                                    \
        o3 = fmaf(xv[S][4], w[P][1], o3);                                    \
        o0 = fmaf(xv[S][2], w[P][2], o0);                                    \
        o1 = fmaf(xv[S][3], w[P][2], o1);                                    \
        o2 = fmaf(xv[S][4], w[P][2], o2);                                    \
        o3 = fmaf(xv[S][5], w[P][2], o3);                                    \
        o0 = fmaf(xv[S][3], w[P][3], o0);                                    \
        o1 = fmaf(xv[S][4], w[P][3], o1);                                    \
        o2 = fmaf(xv[S][5], w[P][3], o2);                                    \
        o3 = fmaf(xv[S][6], w[P][3], o3);                                    \
    } while (0)

#define CS(SA, SB, SC, SD, PO) do {                                          \
        float o0 = 0.f, o1 = 0.f, o2 = 0.f, o3 = 0.f;                        \
        ACCP(SA, 0); ACCP(SB, 1); ACCP(SC, 2); ACCP(SD, 3);                  \
        if (lv) { (PO)[0] = o0; (PO)[1] = o1; }                              \
        (PO)[2] = o2;                                                        \
        (PO)[3] = o3;                                                        \
    } while (0)

    // extra cols 126..128 for g==31 (xv[.][4..7] = input cols 124..127;
    // cols 128,129 are zero pad)
#define XROW(S, P) do {                                                      \
        e0 = fmaf(xv[S][4], w[P][0], e0);                                    \
        e0 = fmaf(xv[S][5], w[P][1], e0);                                    \
        e0 = fmaf(xv[S][6], w[P][2], e0);                                    \
        e0 = fmaf(xv[S][7], w[P][3], e0);                                    \
        e1 = fmaf(xv[S][5], w[P][0], e1);                                    \
        e1 = fmaf(xv[S][6], w[P][1], e1);                                    \
        e1 = fmaf(xv[S][7], w[P][2], e1);                                    \
        e2 = fmaf(xv[S][6], w[P][0], e2);                                    \
        e2 = fmaf(xv[S][7], w[P][1], e2);                                    \
    } while (0)

#define CSX(SA, SB, SC, SD, PO) do {                                         \
        if (g == 31) {                                                       \
            float e0 = 0.f, e1 = 0.f, e2 = 0.f;                              \
            XROW(SA, 0); XROW(SB, 1); XROW(SC, 2); XROW(SD, 3);              \
            (PO)[4] = e0; (PO)[5] = e1; (PO)[6] = e2;  /* cols 126..128 */   \
        }                                                                    \
    } while (0)

    {
        float* po = oi + (size_t)(64 * s + 4 * c) * 129 + 4 * g - 2;
        LLOAD(0, 0); LLOAD(1, 1); LLOAD(2, 2); LLOAD(3, 3);
        CS(0, 1, 2, 3, po); CSX(0, 1, 2, 3, po); LLOAD(0, 4); po += 129;
        CS(1, 2, 3, 0, po); CSX(1, 2, 3, 0, po); LLOAD(1, 5); po += 129;
        CS(2, 3, 0, 1, po); CSX(2, 3, 0, 1, po); LLOAD(2, 6); po += 129;
        CS(3, 0, 1, 2, po); CSX(3, 0, 1, 2, po); po += 129;
        if (s == 1 && c == 15) {                 // out row 128: slots 64..67
            LLOAD(3, 7);
            CS(0, 1, 2, 3, po); CSX(0, 1, 2, 3, po);
        }
    }

#undef LLOAD
#undef ACCP
#undef CS
#undef XROW
#undef CSX
}

extern "C" void kernel_launch(void* const* d_in, const int* in_sizes, int n_in,
                              void* d_out, int out_size, void* d_ws, size_t ws_size,
                              hipStream_t stream) {
    const float* x    = (const float*)d_in[0];
    const float* kern = (const float*)d_in[1];
    float* out        = (float*)d_out;

    // 4096 images * 2 halves = 8192 blocks
    dim3 grid(8192), block(512);
    hipLaunchKernelGGL(blur_half, grid, block, 0, stream, x, kern, out);
}